// Round 15
// baseline (297.302 us; speedup 1.0000x reference)
//
#include <hip/hip_runtime.h>
#include <hip/hip_bf16.h>
#include <math.h>

// Problem constants
#define B_    32
#define IC    512
#define OC    256
#define HW    32
#define OHW   64

// ws layout:
//   xcl  at offset 0:          bf16 [32][34][34][512]  = 37,879,808 B (zero-padded channels-last)
//   Amat at offset 37,879,808: bf16 [1024][4608]       =  9,437,184 B
#define WS_AMAT_OFF 37879808ull

typedef __attribute__((ext_vector_type(8))) short short8;
typedef __attribute__((ext_vector_type(4))) float f32x4;
typedef __attribute__((ext_vector_type(2))) float f32x2;

#define GPTR(x) ((const __attribute__((address_space(1))) char*)(x))
#define LPTR(x) ((__attribute__((address_space(3))) char*)(x))

// ---------------------------------------------------------------------------
// Weight transform. M-row order (oc*4 + p): 4 consecutive C-rows per lane are
// the 4 parities of one oc -> coalesced 2x2 output quads in the epilogue.
__global__ __launch_bounds__(256) void wtrans(const float* __restrict__ w,
                                              __hip_bfloat16* __restrict__ Amat) {
    int t = blockIdx.x * blockDim.x + threadIdx.x;  // 131072 threads
    int ic = t & 511, oc = t >> 9;

    const float gain = 1.0f / sqrtf((float)(IC * 9));
    float wl[3][3];
    const float* wp = w + ((size_t)oc * IC + ic) * 9;
#pragma unroll
    for (int i = 0; i < 3; ++i)
#pragma unroll
        for (int j = 0; j < 3; ++j) wl[i][j] = wp[i * 3 + j] * gain;

    const float f1[4] = {1.f, 3.f, 3.f, 1.f};
    float g2[6][6];
#pragma unroll
    for (int s = 0; s < 6; ++s)
#pragma unroll
        for (int tt = 0; tt < 6; ++tt) {
            float acc = 0.f;
#pragma unroll
            for (int i = 0; i < 3; ++i)
#pragma unroll
                for (int j = 0; j < 3; ++j) {
                    int a = s - 2 + i, b = tt - 2 + j;
                    if (a >= 0 && a < 4 && b >= 0 && b < 4)
                        acc += wl[i][j] * f1[a] * f1[b] * 0.0625f;
                }
            g2[s][tt] = acc;
        }

#pragma unroll
    for (int pm = 0; pm < 2; ++pm)
#pragma unroll
        for (int pn = 0; pn < 2; ++pn)
#pragma unroll
            for (int k = 0; k < 3; ++k)
#pragma unroll
                for (int l = 0; l < 3; ++l) {
                    int p = pm * 2 + pn;
                    size_t idx = ((size_t)(oc * 4 + p) * 4608) + (k * 3 + l) * 512 + ic;
                    Amat[idx] = __float2bfloat16(g2[2 * k + 1 - pm][2 * l + 1 - pn]);
                }
}

// ---------------------------------------------------------------------------
// x (fp32 NCHW) -> xcl (bf16, [b][34][34][512], zero halo), via LDS transpose.
__global__ __launch_bounds__(256) void xprep(const float* __restrict__ x,
                                             __hip_bfloat16* __restrict__ xcl) {
    int blk = blockIdx.x;            // 32*34 blocks
    int b = blk / 34, h = blk % 34;
    __hip_bfloat16* orow = xcl + (size_t)(b * 34 + h) * 34 * 512;
    int t = threadIdx.x;
    bool hin = (h >= 1 && h <= 32);

    for (int i = t; i < 2 * 512; i += 256) {
        int wsel = i >> 9, ic = i & 511;
        orow[(size_t)(wsel * 33) * 512 + ic] = __float2bfloat16(0.f);
    }

    __shared__ float ls[16][33];
    int icl_r = t >> 5, wv_r = t & 31;
    int wv_w = t >> 3, icl_w = t & 7;

    for (int ic0 = 0; ic0 < 512; ic0 += 16) {
        __syncthreads();
#pragma unroll
        for (int pp = 0; pp < 2; ++pp) {
            int icll = icl_r + pp * 8;
            float v = 0.f;
            if (hin) v = x[(((size_t)b * IC + ic0 + icll) * HW + (h - 1)) * HW + wv_r];
            ls[icll][wv_r] = v;
        }
        __syncthreads();
#pragma unroll
        for (int pp = 0; pp < 2; ++pp) {
            int icll = icl_w + pp * 8;
            orow[(size_t)(wv_w + 1) * 512 + ic0 + icll] = __float2bfloat16(ls[icll][wv_w]);
        }
    }
}

// ---------------------------------------------------------------------------
// Implicit-GEMM, 256x256 tile, BK=32, *** 4 FAT WAVES (2Mx2N, 128x128 each) ***
// R15 lever: fragment-read REDUCTION, not schedule. 8 waves x (8A+4B) frags
// = 96 KB/tile -> 4 waves x (8A+8B) = 64 KB/tile (-33% of the LDS term in
// the empirically-validated serial wall MFMA(1242) + LDS(1130) cyc/tile).
// MFMA time unchanged (256 MFMA/CU/tile; 64 indep accumulators/wave saturate
// each SIMD's matrix pipe single-wave, m119). VGPR: 256 acc + 64 frag + addr
// ~= 350 <= 512, legal at 1 wave/SIMD (launch_bounds(256,1); 128 KB LDS
// forces 1 block/CU regardless). Losing wave-TLP costs nothing measured:
// 8 schedule variants showed zero cross-wave overlap (wall = serial sum).
// Keeps: ring-4 + counted vmcnt(8) (R4 accounting, 8 loads/thread/tile),
// R4 zero-conflict swizzle, XCD remap (FETCH 610->281 MB), quad epilogue.
__global__ __launch_bounds__(256, 1) void gemm_conv(const __hip_bfloat16* __restrict__ Amat,
                                                    const __hip_bfloat16* __restrict__ xcl,
                                                    const float* __restrict__ bias,
                                                    float* __restrict__ out) {
    __shared__ __align__(1024) char lds[4 * 32768];

    const int NT = 144;              // K-tiles of 32 (K = 4608)
    int bid = blockIdx.x;            // 512 blocks
    // XCD remap (verified R7/R8): xcd = bid&7; 4 mt co-resident per slab.
    int mt = bid >> 7;                              // 0..3
    int nt = (bid & 7) * 16 + ((bid >> 3) & 15);    // 0..127
    int tid = threadIdx.x;           // 256 threads = 4 waves
    int wid = tid >> 6;
    int lane = tid & 63;
    int wr = wid >> 1;               // 0..1  (M half: rows wr*128..+127)
    int wc = wid & 1;                // 0..1  (N half: cols wc*128..+127)
    int q = lane >> 4;               // k-granule
    int lr = lane & 15;

    // ---- staging constants (swizzle folded into global source) ----
    int r0 = tid >> 2;               // 0..63 (round i adds i*64 to the row)
    int slt = tid & 3;               // LDS slot in 64-B row
    int g_ = slt ^ ((r0 >> 1) & 3);  // i*64 doesn't touch bits 1-2 of row>>1

    const char* GA = (const char*)Amat;
    const char* GB = (const char*)xcl;

    size_t asrc[4];
    int bsrc[4];
#pragma unroll
    for (int i = 0; i < 4; ++i) {
        int rr = i * 64 + r0;                           // 0..255 tile-local row
        asrc[i] = (size_t)(mt * 256 + rr) * 9216 + g_ * 16;
        int n = nt * 256 + rr;
        int bb = n >> 10, uu = (n >> 5) & 31, vv = n & 31;
        bsrc[i] = ((bb * 34 + uu) * 34 + vv) * 1024 + g_ * 16;
    }
    int dstT = tid * 16;             // byte offset within a 4-KB round chunk

    // ---- ds_read bases (R4 zero-conflict swizzle; row bits re-verified:
    //      wr*128, wc*128, mi*16, ni*16 don't touch (row>>1)&3) ----
    int qs = (q ^ ((lr >> 1) & 3)) << 4;
    int A0 = (wr * 128 + lr) * 64 + qs;            // + mi*1024 imm
    int B0 = 16384 + (wc * 128 + lr) * 64 + qs;    // + ni*1024 imm

    f32x4 acc[8][8];
#pragma unroll
    for (int mi = 0; mi < 8; ++mi)
#pragma unroll
        for (int ni = 0; ni < 8; ++ni) acc[mi][ni] = (f32x4){0.f, 0.f, 0.f, 0.f};

    auto STAGE = [&](int ks, int bufi) {   // 8 gload_lds/thread: A 4, B 4
        int kl = ks >> 4;
        int kh = (kl * 11) >> 5;     // kl/3 for kl in [0,9)
        int kw = kl - 3 * kh;
        int bo = (kh * 34 + kw) * 1024 + (ks & 15) * 64;
        size_t ao = (size_t)ks * 64;
        char* L = lds + bufi * 32768;
#pragma unroll
        for (int i = 0; i < 4; ++i)
            __builtin_amdgcn_global_load_lds(GPTR(GA + asrc[i] + ao),
                                             LPTR(L + i * 4096 + dstT), 16, 0, 0);
#pragma unroll
        for (int i = 0; i < 4; ++i)
            __builtin_amdgcn_global_load_lds(GPTR(GB + bsrc[i] + bo),
                                             LPTR(L + 16384 + i * 4096 + dstT), 16, 0, 0);
    };

    // prologue: fill pipeline depth 2
    STAGE(0, 0);
    STAGE(1, 1);

    for (int t = 0; t < NT; ++t) {
        // counted wait: oldest 8 (tile t) landed; tile t+1's 8 stay in flight.
        // WAR safety (ring-4, distance-2): STAGE(t+2) writes buf (t-2)&3,
        // whose reads retired before iter t-1's barrier -> 1 barrier/iter ok.
        asm volatile("s_waitcnt vmcnt(8)" ::: "memory");
        __builtin_amdgcn_s_barrier();
        __builtin_amdgcn_sched_barrier(0);

        STAGE(t + 2 < NT ? t + 2 : NT - 1, (t + 2) & 3);

        const char* Lc = lds + (t & 3) * 32768;
        short8 aF[8], bF[8];
#pragma unroll
        for (int mi = 0; mi < 8; ++mi) aF[mi] = *(const short8*)(Lc + A0 + mi * 1024);
#pragma unroll
        for (int ni = 0; ni < 8; ++ni) bF[ni] = *(const short8*)(Lc + B0 + ni * 1024);

        __builtin_amdgcn_s_setprio(1);
#pragma unroll
        for (int mi = 0; mi < 8; ++mi)
#pragma unroll
            for (int ni = 0; ni < 8; ++ni)
                acc[mi][ni] = __builtin_amdgcn_mfma_f32_16x16x32_bf16(
                    aF[mi], bF[ni], acc[mi][ni], 0, 0, 0);
        __builtin_amdgcn_s_setprio(0);
    }
    asm volatile("s_waitcnt vmcnt(0)" ::: "memory");   // drain clamped stages

    // ---- epilogue: 4 acc regs per frag = 4 parities of one oc -> 2x2 quad ----
    const float s2 = 1.41421356237309515f;
#pragma unroll
    for (int mi = 0; mi < 8; ++mi) {
        int oc = mt * 64 + wr * 32 + mi * 4 + q;
        float bv = bias[oc];
#pragma unroll
        for (int ni = 0; ni < 8; ++ni) {
            int n = nt * 256 + wc * 128 + ni * 16 + lr;
            int b = n >> 10, u = (n >> 5) & 31, v = n & 31;
            float y0 = acc[mi][ni][0] + bv;
            float y1 = acc[mi][ni][1] + bv;
            float y2 = acc[mi][ni][2] + bv;
            float y3 = acc[mi][ni][3] + bv;
            y0 = (y0 >= 0.f ? y0 : 0.2f * y0) * s2;
            y1 = (y1 >= 0.f ? y1 : 0.2f * y1) * s2;
            y2 = (y2 >= 0.f ? y2 : 0.2f * y2) * s2;
            y3 = (y3 >= 0.f ? y3 : 0.2f * y3) * s2;
            size_t base = (((size_t)b * OC + oc) * OHW + 2 * u) * OHW + 2 * v;
            *(f32x2*)(out + base)       = (f32x2){y0, y1};   // row 2u:   p=(0,0),(0,1)
            *(f32x2*)(out + base + OHW) = (f32x2){y2, y3};   // row 2u+1: p=(1,0),(1,1)
        }
    }
}

// ---------------------------------------------------------------------------
extern "C" void kernel_launch(void* const* d_in, const int* in_sizes, int n_in,
                              void* d_out, int out_size, void* d_ws, size_t ws_size,
                              hipStream_t stream) {
    const float* x    = (const float*)d_in[0];
    const float* w    = (const float*)d_in[1];
    const float* bias = (const float*)d_in[2];
    float* out = (float*)d_out;

    __hip_bfloat16* xcl  = (__hip_bfloat16*)d_ws;
    __hip_bfloat16* Amat = (__hip_bfloat16*)((char*)d_ws + WS_AMAT_OFF);

    xprep<<<32 * 34, 256, 0, stream>>>(x, xcl);
    wtrans<<<(OC * IC) / 256, 256, 0, stream>>>(w, Amat);
    // grid: 4 M-tiles * 128 N-tiles = 512 blocks, 256 threads (4 fat waves)
    gemm_conv<<<512, 256, 0, stream>>>(Amat, xcl, bias, out);
}